// Round 7
// baseline (582.969 us; speedup 1.0000x reference)
//
#include <hip/hip_runtime.h>

// ---------------------------------------------------------------------------
// Self-attention, fp16-MFMA pipeline.
// R12 = R10 (proven 128x128 2-barrier core + QK^T = X(WqWk^T/8)X^T algebra)
// with occupancy/tail fixes only — core K-loop untouched:
//   - __launch_bounds__(256, 5): LDS 32KB/block -> exactly 5 blocks/CU
//     (160KB), up from measured ~2.5.  More cross-block overlap (m114) and
//     smaller dispatch tails.
//   - XG and Vt merged into ONE 1536-block launch (proj_dual): the two
//     768-block dispatches were each ~1.2 occupancy-rounds (tail-bound).
//     Single core call site -> single 32KB LDS allocation.
// R11's fp8 P-V is dead (softmax-mass underflow + RTN noise exceeds the
// absmax budget for ANY fp8 format) — not retried.
// ---------------------------------------------------------------------------

typedef _Float16 f16;
typedef _Float16 f16x8 __attribute__((ext_vector_type(8)));
typedef _Float16 f16x4 __attribute__((ext_vector_type(4)));
typedef float f32x4 __attribute__((ext_vector_type(4)));

__device__ __forceinline__ void gload16(const void* g, void* l) {
    __builtin_amdgcn_global_load_lds((__attribute__((address_space(1))) void*)g,
                                     (__attribute__((address_space(3))) void*)l,
                                     16, 0, 0);
}

// MODE 0: C[row,col] = (OutT)(acc * oscale)
// MODE 1: C = f16(exp(acc - 12)); atomicAdd row sums into R[row]
// MODE 2: C = (OutT)(acc / R[row])
// A,B,C,R pre-offset for batch; computes the 128x128 tile at (row0, col0).
template <int MODE, typename OutT>
__device__ __forceinline__ void gemm_core(
    const f16* __restrict__ A, const f16* __restrict__ B,
    OutT* __restrict__ C, float* __restrict__ R,
    int K, int lda, int ldb, int ldc, long row0, long col0, float oscale)
{
    __shared__ __align__(16) f16 lA[128 * 64];
    __shared__ __align__(16) f16 lB[128 * 64];

    const int tid  = threadIdx.x;
    const int wave = tid >> 6;
    const int lane = tid & 63;

    // Staging: pass p (0..3), LDS chunk = p*256 + tid; row = p*32 + (tid>>3),
    // dst col-chunk = tid&7; SOURCE col-chunk = (tid&7) ^ (row&7).
    const int r0 = tid >> 3;                       // 0..31
    const int cs = (((tid & 7) ^ (r0 & 7)) * 8);   // swizzled source col (f16)
    const f16* ag0 = A + (row0 +      r0) * lda + cs;
    const f16* ag1 = A + (row0 + 32 + r0) * lda + cs;
    const f16* ag2 = A + (row0 + 64 + r0) * lda + cs;
    const f16* ag3 = A + (row0 + 96 + r0) * lda + cs;
    const f16* bg0 = B + (col0 +      r0) * ldb + cs;
    const f16* bg1 = B + (col0 + 32 + r0) * ldb + cs;
    const f16* bg2 = B + (col0 + 64 + r0) * ldb + cs;
    const f16* bg3 = B + (col0 + 96 + r0) * ldb + cs;
    f16* lA0 = lA +        wave * 512;   // pass bases: wave-uniform + lane*16B
    f16* lA1 = lA + 2048 + wave * 512;
    f16* lA2 = lA + 4096 + wave * 512;
    f16* lA3 = lA + 6144 + wave * 512;
    f16* lB0 = lB +        wave * 512;
    f16* lB1 = lB + 2048 + wave * 512;
    f16* lB2 = lB + 4096 + wave * 512;
    f16* lB3 = lB + 6144 + wave * 512;

    // 4 waves in 2x2 -> each wave owns 64x64 = 4x4 MFMA tiles of 16x16.
    const int wm = wave >> 1, wn = wave & 1;
    const int fl = lane & 15;            // m (A) / n (B) within tile
    const int q  = lane >> 4;            // k-chunk within 32-k half
    // fragment read: row*64 + ((g ^ (row&7)) * 8); row&7 == fl&7.
    // kk=0: g=q -> co; kk=32: g=q^4 -> co^32.
    const int co = ((q ^ (fl & 7)) * 8);
    const f16* paw = lA + (wm * 64 + fl) * 64;
    const f16* pbw = lB + (wn * 64 + fl) * 64;

    f32x4 acc[4][4] = {};

    for (int k0 = 0; k0 < K; k0 += 64) {
        __syncthreads();                 // LDS free from previous iteration
        gload16(ag0, lA0); gload16(ag1, lA1);
        gload16(ag2, lA2); gload16(ag3, lA3);
        gload16(bg0, lB0); gload16(bg1, lB1);
        gload16(bg2, lB2); gload16(bg3, lB3);
        ag0 += 64; ag1 += 64; ag2 += 64; ag3 += 64;
        bg0 += 64; bg1 += 64; bg2 += 64; bg3 += 64;
        __syncthreads();                 // drains vmcnt -> staged data visible

#pragma unroll
        for (int kk = 0; kk < 64; kk += 32) {
            const int o = co ^ (kk == 0 ? 0 : 32);
            f16x8 a[4], b[4];
#pragma unroll
            for (int i = 0; i < 4; ++i)
                a[i] = *(const f16x8*)(paw + i * 1024 + o);
#pragma unroll
            for (int j = 0; j < 4; ++j)
                b[j] = *(const f16x8*)(pbw + j * 1024 + o);
#pragma unroll
            for (int i = 0; i < 4; ++i)
#pragma unroll
                for (int j = 0; j < 4; ++j)
                    acc[i][j] = __builtin_amdgcn_mfma_f32_16x16x32_f16(
                        a[i], b[j], acc[i][j], 0, 0, 0);
        }
    }

    // Epilogue: D[m][n], n = lane&15, m = (lane>>4)*4 + r
    const int rq = (lane >> 4) * 4;
#pragma unroll
    for (int i = 0; i < 4; ++i) {
#pragma unroll
        for (int r = 0; r < 4; ++r) {
            const long row = row0 + wm * 64 + i * 16 + rq + r;
            if (MODE == 0) {
#pragma unroll
                for (int j = 0; j < 4; ++j) {
                    const long col = col0 + wn * 64 + j * 16 + fl;
                    C[row * ldc + col] = (OutT)(acc[i][j][r] * oscale);
                }
            } else if (MODE == 1) {
                float s = 0.f;
#pragma unroll
                for (int j = 0; j < 4; ++j) {
                    const long col = col0 + wn * 64 + j * 16 + fl;
                    float e = __expf(acc[i][j][r] - 12.0f);   // scale in GT
                    C[row * ldc + col] = (OutT)e;
                    s += e;
                }
                s += __shfl_xor(s, 1, 16);
                s += __shfl_xor(s, 2, 16);
                s += __shfl_xor(s, 4, 16);
                s += __shfl_xor(s, 8, 16);
                if (fl == 0) atomicAdd(&R[row], s);
            } else {
                const float inv = 1.0f / R[row];
#pragma unroll
                for (int j = 0; j < 4; ++j) {
                    const long col = col0 + wn * 64 + j * 16 + fl;
                    C[row * ldc + col] = (OutT)(acc[i][j][r] * inv);
                }
            }
        }
    }
}

template <int MODE, typename OutT>
__global__ __launch_bounds__(256, 5)
void gemm_bt(const f16* __restrict__ A, const f16* __restrict__ B,
             OutT* __restrict__ C, float* R, int K, int lda, int ldb, int ldc,
             long sA, long sB, long sC, float oscale)
{
    // XCD-aware remap (bijection when nb % 8 == 0)
    const unsigned gx = gridDim.x, gy = gridDim.y;
    const unsigned nb = gx * gy * gridDim.z;
    unsigned lin = blockIdx.x + gx * (blockIdx.y + gy * blockIdx.z);
    if ((nb & 7u) == 0u) lin = (lin & 7u) * (nb >> 3) + (lin >> 3);
    const unsigned bx = lin % gx;
    const unsigned rem = lin / gx;
    const unsigned by = rem % gy;
    const unsigned bz = rem / gy;

    gemm_core<MODE, OutT>(A + (long)bz * sA, B + (long)bz * sB,
                          C + (long)bz * sC,
                          (MODE != 0) ? (R + (long)bz * 2048) : nullptr,
                          K, lda, ldb, ldc,
                          (long)by * 128, (long)bx * 128, oscale);
}

// Merged XG + Vt launch: grid (16, 6, 16), 1536 blocks (%8==0 -> remap ok).
//   bz < 8 : Vt_b = wt2 @ xh_b^T  (M=768, N=2048, K=768), batch bz
//   bz >= 8: XG = xh @ GT^T       (M=16384, N=768, K=768), 96 blocks per bz
__global__ __launch_bounds__(256, 5)
void proj_dual(const f16* __restrict__ xh, const f16* __restrict__ GT,
               f16* __restrict__ XG, const f16* __restrict__ wt2,
               f16* __restrict__ Vt)
{
    const unsigned nb = 16u * 6u * 16u;
    unsigned lin = blockIdx.x + 16u * (blockIdx.y + 6u * blockIdx.z);
    lin = (lin & 7u) * (nb >> 3) + (lin >> 3);
    const unsigned bx = lin % 16u;
    const unsigned rem = lin / 16u;
    const unsigned by = rem % 6u;
    const unsigned bz = rem / 6u;

    const f16 *Aa, *Bb;
    f16* Cc;
    int ldc_;
    long r0_, c0_;
    if (bz < 8u) {                      // Vt batch bz
        Aa = wt2;
        Bb = xh + (long)bz * 1572864;
        Cc = Vt + (long)bz * 1572864;
        ldc_ = 2048;
        r0_ = (long)by * 128;           // by < 6  -> rows 0..767
        c0_ = (long)bx * 128;           // bx < 16 -> cols 0..2047
    } else {                            // XG, 96 blocks per bz-slice
        const unsigned l = bx + 16u * by;           // 0..95
        const unsigned xbx = l % 6u;
        const unsigned xby = (bz - 8u) * 16u + l / 6u;   // 0..127
        Aa = xh;
        Bb = GT;
        Cc = XG;
        ldc_ = 768;
        r0_ = (long)xby * 128;
        c0_ = (long)xbx * 128;
    }
    gemm_core<0, f16>(Aa, Bb, Cc, nullptr, 768, 768, 768, ldc_, r0_, c0_, 1.0f);
}

__global__ void cvt_f32_f16(const float* __restrict__ in, f16* __restrict__ out,
                            int n4)
{
    int i = blockIdx.x * blockDim.x + threadIdx.x;
    int stride = gridDim.x * blockDim.x;
    for (; i < n4; i += stride) {
        float4 v = ((const float4*)in)[i];
        f16x4 h;
        h[0] = (f16)v.x; h[1] = (f16)v.y; h[2] = (f16)v.z; h[3] = (f16)v.w;
        ((f16x4*)out)[i] = h;
    }
}

// wT[o][d] = f16(w[d][o]) for ONE 768x768 matrix; grid (24, 24), 256 threads
__global__ void wtrans(const float* __restrict__ w, f16* __restrict__ wT)
{
    __shared__ float t[32][33];
    const int o0 = blockIdx.x * 32, d0 = blockIdx.y * 32;
    const int tx = threadIdx.x & 31, ty = threadIdx.x >> 5;
    const float* src = w + (size_t)d0 * 768 + o0;
#pragma unroll
    for (int r = 0; r < 32; r += 8)
        t[ty + r][tx] = src[(size_t)(ty + r) * 768 + tx];
    __syncthreads();
    f16* dst = wT + (size_t)o0 * 768 + d0;
#pragma unroll
    for (int r = 0; r < 32; r += 8)
        dst[(size_t)(ty + r) * 768 + tx] = (f16)t[tx][ty + r];
}

extern "C" void kernel_launch(void* const* d_in, const int* in_sizes, int n_in,
                              void* d_out, int out_size, void* d_ws, size_t ws_size,
                              hipStream_t stream)
{
    (void)in_sizes; (void)n_in; (void)out_size; (void)ws_size;
    const float* x = (const float*)d_in[0];
    const float* w = (const float*)d_in[1];
    float* out = (float*)d_out;

    // B=8, S=2048, D=O=768; BS = 16384
    const long NX  = 12582912;     // 16384*768
    const long NW  = 1769472;      // 3*768*768
    const long NW1 = 589824;       // 768*768
    f16* xh  = (f16*)d_ws;         // [16384][768]   X (alive thru MODE1)
    f16* wh  = xh + NX;            // [3][768][768]  f16(w), dead after GT
    f16* wt2 = wh + NW;            // [768][768]     Wv^T, dead after proj_dual
    f16* GT  = wt2 + NW1;          // [768][768]     (Wk Wq^T)/8
    f16* XG  = GT + NW1;           // [16384][768]   X G / 8
    f16* Vt  = XG + NX;            // [8][768][2048]
    f16* Sc  = Vt + NX;            // [8][2048][2048] exp-logits (unnormalized)
    float* R = (float*)wh;         // [8][2048] row sums — aliases dead wh
    // total ws: (3*NX + NW + 2*NW1 + 8*2048*2048) * 2 B = 148,504,576 B

    cvt_f32_f16<<<2048, 256, 0, stream>>>(x, xh, (int)(NX / 4));
    cvt_f32_f16<<<1024, 256, 0, stream>>>(w, wh, (int)(NW / 4));
    // wt2[o][d] = f16(w[2][d][o])
    wtrans<<<dim3(24, 24, 1), 256, 0, stream>>>(w + 2 * NW1, wt2);

    // GT = (wh1 @ wh0^T) / 8 : GT[i][j] = sum_o Wk[i][o] Wq[j][o] / 8
    gemm_bt<0, f16><<<dim3(6, 6, 1), 256, 0, stream>>>(
        wh + NW1, wh, GT, nullptr, 768, 768, 768, 768, 0, 0, 0, 0.125f);
    // XG = xh @ GT^T  and  Vt_b = wt2 @ xh_b^T, one 1536-block launch
    proj_dual<<<dim3(16, 6, 16), 256, 0, stream>>>(xh, GT, XG, wt2, Vt);
    // wh dead from here; R aliases it
    hipMemsetAsync(R, 0, 8 * 2048 * sizeof(float), stream);
    // Ps_b = exp(XG_b @ xh_b^T - 12) + rowsum atomics (M=2048,N=2048,K=768)
    gemm_bt<1, f16><<<dim3(16, 16, 8), 256, 0, stream>>>(
        XG, xh, Sc, R, 768, 768, 768, 2048, 1572864, 1572864, 4194304, 1.0f);
    // out_b = (Ps_b @ Vt_b^T) / R[row]  (M=2048, N=768, K=2048), fp32 out
    gemm_bt<2, float><<<dim3(6, 16, 8), 256, 0, stream>>>(
        Sc, Vt, out, R, 2048, 2048, 2048, 768, 4194304, 1572864, 1572864, 1.0f);
}

// Round 8
// 287.395 us; speedup vs baseline: 2.0285x; 2.0285x over previous
//
#include <hip/hip_runtime.h>

// ---------------------------------------------------------------------------
// Self-attention, fp16-MFMA pipeline.
// R13 = R10 (proven 128x128 2-barrier core, launch_bounds(256,2), QK^T =
// X(WqWk^T/8)X^T algebra) + R12's proj_dual merge ONLY.
// R12 lesson (counters): __launch_bounds__(256,5) cut the VGPR budget to
// ~100 -> accumulator spill -> 493MB scratch writes, MODE1 208us.  This
// kernel requires the (256,2) register budget; do not raise min-occupancy.
// ---------------------------------------------------------------------------

typedef _Float16 f16;
typedef _Float16 f16x8 __attribute__((ext_vector_type(8)));
typedef _Float16 f16x4 __attribute__((ext_vector_type(4)));
typedef float f32x4 __attribute__((ext_vector_type(4)));

__device__ __forceinline__ void gload16(const void* g, void* l) {
    __builtin_amdgcn_global_load_lds((__attribute__((address_space(1))) void*)g,
                                     (__attribute__((address_space(3))) void*)l,
                                     16, 0, 0);
}

// MODE 0: C[row,col] = (OutT)(acc * oscale)
// MODE 1: C = f16(exp(acc - 12)); atomicAdd row sums into R[row]
// MODE 2: C = (OutT)(acc / R[row])
// A,B,C,R pre-offset for batch; computes the 128x128 tile at (row0, col0).
template <int MODE, typename OutT>
__device__ __forceinline__ void gemm_core(
    const f16* __restrict__ A, const f16* __restrict__ B,
    OutT* __restrict__ C, float* __restrict__ R,
    int K, int lda, int ldb, int ldc, long row0, long col0, float oscale)
{
    __shared__ __align__(16) f16 lA[128 * 64];
    __shared__ __align__(16) f16 lB[128 * 64];

    const int tid  = threadIdx.x;
    const int wave = tid >> 6;
    const int lane = tid & 63;

    // Staging: pass p (0..3), LDS chunk = p*256 + tid; row = p*32 + (tid>>3),
    // dst col-chunk = tid&7; SOURCE col-chunk = (tid&7) ^ (row&7).
    const int r0 = tid >> 3;                       // 0..31
    const int cs = (((tid & 7) ^ (r0 & 7)) * 8);   // swizzled source col (f16)
    const f16* ag0 = A + (row0 +      r0) * lda + cs;
    const f16* ag1 = A + (row0 + 32 + r0) * lda + cs;
    const f16* ag2 = A + (row0 + 64 + r0) * lda + cs;
    const f16* ag3 = A + (row0 + 96 + r0) * lda + cs;
    const f16* bg0 = B + (col0 +      r0) * ldb + cs;
    const f16* bg1 = B + (col0 + 32 + r0) * ldb + cs;
    const f16* bg2 = B + (col0 + 64 + r0) * ldb + cs;
    const f16* bg3 = B + (col0 + 96 + r0) * ldb + cs;
    f16* lA0 = lA +        wave * 512;   // pass bases: wave-uniform + lane*16B
    f16* lA1 = lA + 2048 + wave * 512;
    f16* lA2 = lA + 4096 + wave * 512;
    f16* lA3 = lA + 6144 + wave * 512;
    f16* lB0 = lB +        wave * 512;
    f16* lB1 = lB + 2048 + wave * 512;
    f16* lB2 = lB + 4096 + wave * 512;
    f16* lB3 = lB + 6144 + wave * 512;

    // 4 waves in 2x2 -> each wave owns 64x64 = 4x4 MFMA tiles of 16x16.
    const int wm = wave >> 1, wn = wave & 1;
    const int fl = lane & 15;            // m (A) / n (B) within tile
    const int q  = lane >> 4;            // k-chunk within 32-k half
    // fragment read: row*64 + ((g ^ (row&7)) * 8); row&7 == fl&7.
    // kk=0: g=q -> co; kk=32: g=q^4 -> co^32.
    const int co = ((q ^ (fl & 7)) * 8);
    const f16* paw = lA + (wm * 64 + fl) * 64;
    const f16* pbw = lB + (wn * 64 + fl) * 64;

    f32x4 acc[4][4] = {};

    for (int k0 = 0; k0 < K; k0 += 64) {
        __syncthreads();                 // LDS free from previous iteration
        gload16(ag0, lA0); gload16(ag1, lA1);
        gload16(ag2, lA2); gload16(ag3, lA3);
        gload16(bg0, lB0); gload16(bg1, lB1);
        gload16(bg2, lB2); gload16(bg3, lB3);
        ag0 += 64; ag1 += 64; ag2 += 64; ag3 += 64;
        bg0 += 64; bg1 += 64; bg2 += 64; bg3 += 64;
        __syncthreads();                 // drains vmcnt -> staged data visible

#pragma unroll
        for (int kk = 0; kk < 64; kk += 32) {
            const int o = co ^ (kk == 0 ? 0 : 32);
            f16x8 a[4], b[4];
#pragma unroll
            for (int i = 0; i < 4; ++i)
                a[i] = *(const f16x8*)(paw + i * 1024 + o);
#pragma unroll
            for (int j = 0; j < 4; ++j)
                b[j] = *(const f16x8*)(pbw + j * 1024 + o);
#pragma unroll
            for (int i = 0; i < 4; ++i)
#pragma unroll
                for (int j = 0; j < 4; ++j)
                    acc[i][j] = __builtin_amdgcn_mfma_f32_16x16x32_f16(
                        a[i], b[j], acc[i][j], 0, 0, 0);
        }
    }

    // Epilogue: D[m][n], n = lane&15, m = (lane>>4)*4 + r
    const int rq = (lane >> 4) * 4;
#pragma unroll
    for (int i = 0; i < 4; ++i) {
#pragma unroll
        for (int r = 0; r < 4; ++r) {
            const long row = row0 + wm * 64 + i * 16 + rq + r;
            if (MODE == 0) {
#pragma unroll
                for (int j = 0; j < 4; ++j) {
                    const long col = col0 + wn * 64 + j * 16 + fl;
                    C[row * ldc + col] = (OutT)(acc[i][j][r] * oscale);
                }
            } else if (MODE == 1) {
                float s = 0.f;
#pragma unroll
                for (int j = 0; j < 4; ++j) {
                    const long col = col0 + wn * 64 + j * 16 + fl;
                    float e = __expf(acc[i][j][r] - 12.0f);   // scale in GT
                    C[row * ldc + col] = (OutT)e;
                    s += e;
                }
                s += __shfl_xor(s, 1, 16);
                s += __shfl_xor(s, 2, 16);
                s += __shfl_xor(s, 4, 16);
                s += __shfl_xor(s, 8, 16);
                if (fl == 0) atomicAdd(&R[row], s);
            } else {
                const float inv = 1.0f / R[row];
#pragma unroll
                for (int j = 0; j < 4; ++j) {
                    const long col = col0 + wn * 64 + j * 16 + fl;
                    C[row * ldc + col] = (OutT)(acc[i][j][r] * inv);
                }
            }
        }
    }
}

template <int MODE, typename OutT>
__global__ __launch_bounds__(256, 2)
void gemm_bt(const f16* __restrict__ A, const f16* __restrict__ B,
             OutT* __restrict__ C, float* R, int K, int lda, int ldb, int ldc,
             long sA, long sB, long sC, float oscale)
{
    // XCD-aware remap (bijection when nb % 8 == 0)
    const unsigned gx = gridDim.x, gy = gridDim.y;
    const unsigned nb = gx * gy * gridDim.z;
    unsigned lin = blockIdx.x + gx * (blockIdx.y + gy * blockIdx.z);
    if ((nb & 7u) == 0u) lin = (lin & 7u) * (nb >> 3) + (lin >> 3);
    const unsigned bx = lin % gx;
    const unsigned rem = lin / gx;
    const unsigned by = rem % gy;
    const unsigned bz = rem / gy;

    gemm_core<MODE, OutT>(A + (long)bz * sA, B + (long)bz * sB,
                          C + (long)bz * sC,
                          (MODE != 0) ? (R + (long)bz * 2048) : nullptr,
                          K, lda, ldb, ldc,
                          (long)by * 128, (long)bx * 128, oscale);
}

// Merged XG + Vt launch: grid (16, 6, 16), 1536 blocks (%8==0 -> remap ok).
//   bz < 8 : Vt_b = wt2 @ xh_b^T  (M=768, N=2048, K=768), batch bz
//   bz >= 8: XG = xh @ GT^T       (M=16384, N=768, K=768), 96 blocks per bz
__global__ __launch_bounds__(256, 2)
void proj_dual(const f16* __restrict__ xh, const f16* __restrict__ GT,
               f16* __restrict__ XG, const f16* __restrict__ wt2,
               f16* __restrict__ Vt)
{
    const unsigned nb = 16u * 6u * 16u;
    unsigned lin = blockIdx.x + 16u * (blockIdx.y + 6u * blockIdx.z);
    lin = (lin & 7u) * (nb >> 3) + (lin >> 3);
    const unsigned bx = lin % 16u;
    const unsigned rem = lin / 16u;
    const unsigned by = rem % 6u;
    const unsigned bz = rem / 6u;

    const f16 *Aa, *Bb;
    f16* Cc;
    int ldc_;
    long r0_, c0_;
    if (bz < 8u) {                      // Vt batch bz
        Aa = wt2;
        Bb = xh + (long)bz * 1572864;
        Cc = Vt + (long)bz * 1572864;
        ldc_ = 2048;
        r0_ = (long)by * 128;           // by < 6  -> rows 0..767
        c0_ = (long)bx * 128;           // bx < 16 -> cols 0..2047
    } else {                            // XG, 96 blocks per bz-slice
        const unsigned l = bx + 16u * by;           // 0..95
        const unsigned xbx = l % 6u;
        const unsigned xby = (bz - 8u) * 16u + l / 6u;   // 0..127
        Aa = xh;
        Bb = GT;
        Cc = XG;
        ldc_ = 768;
        r0_ = (long)xby * 128;
        c0_ = (long)xbx * 128;
    }
    gemm_core<0, f16>(Aa, Bb, Cc, nullptr, 768, 768, 768, ldc_, r0_, c0_, 1.0f);
}

__global__ void cvt_f32_f16(const float* __restrict__ in, f16* __restrict__ out,
                            int n4)
{
    int i = blockIdx.x * blockDim.x + threadIdx.x;
    int stride = gridDim.x * blockDim.x;
    for (; i < n4; i += stride) {
        float4 v = ((const float4*)in)[i];
        f16x4 h;
        h[0] = (f16)v.x; h[1] = (f16)v.y; h[2] = (f16)v.z; h[3] = (f16)v.w;
        ((f16x4*)out)[i] = h;
    }
}

// wT[o][d] = f16(w[d][o]) for ONE 768x768 matrix; grid (24, 24), 256 threads
__global__ void wtrans(const float* __restrict__ w, f16* __restrict__ wT)
{
    __shared__ float t[32][33];
    const int o0 = blockIdx.x * 32, d0 = blockIdx.y * 32;
    const int tx = threadIdx.x & 31, ty = threadIdx.x >> 5;
    const float* src = w + (size_t)d0 * 768 + o0;
#pragma unroll
    for (int r = 0; r < 32; r += 8)
        t[ty + r][tx] = src[(size_t)(ty + r) * 768 + tx];
    __syncthreads();
    f16* dst = wT + (size_t)o0 * 768 + d0;
#pragma unroll
    for (int r = 0; r < 32; r += 8)
        dst[(size_t)(ty + r) * 768 + tx] = (f16)t[tx][ty + r];
}

extern "C" void kernel_launch(void* const* d_in, const int* in_sizes, int n_in,
                              void* d_out, int out_size, void* d_ws, size_t ws_size,
                              hipStream_t stream)
{
    (void)in_sizes; (void)n_in; (void)out_size; (void)ws_size;
    const float* x = (const float*)d_in[0];
    const float* w = (const float*)d_in[1];
    float* out = (float*)d_out;

    // B=8, S=2048, D=O=768; BS = 16384
    const long NX  = 12582912;     // 16384*768
    const long NW  = 1769472;      // 3*768*768
    const long NW1 = 589824;       // 768*768
    f16* xh  = (f16*)d_ws;         // [16384][768]   X (alive thru MODE1)
    f16* wh  = xh + NX;            // [3][768][768]  f16(w), dead after GT
    f16* wt2 = wh + NW;            // [768][768]     Wv^T, dead after proj_dual
    f16* GT  = wt2 + NW1;          // [768][768]     (Wk Wq^T)/8
    f16* XG  = GT + NW1;           // [16384][768]   X G / 8
    f16* Vt  = XG + NX;            // [8][768][2048]
    f16* Sc  = Vt + NX;            // [8][2048][2048] exp-logits (unnormalized)
    float* R = (float*)wh;         // [8][2048] row sums — aliases dead wh
    // total ws: (3*NX + NW + 2*NW1 + 8*2048*2048) * 2 B = 148,504,576 B

    cvt_f32_f16<<<2048, 256, 0, stream>>>(x, xh, (int)(NX / 4));
    cvt_f32_f16<<<1024, 256, 0, stream>>>(w, wh, (int)(NW / 4));
    // wt2[o][d] = f16(w[2][d][o])
    wtrans<<<dim3(24, 24, 1), 256, 0, stream>>>(w + 2 * NW1, wt2);

    // GT = (wh1 @ wh0^T) / 8 : GT[i][j] = sum_o Wk[i][o] Wq[j][o] / 8
    gemm_bt<0, f16><<<dim3(6, 6, 1), 256, 0, stream>>>(
        wh + NW1, wh, GT, nullptr, 768, 768, 768, 768, 0, 0, 0, 0.125f);
    // XG = xh @ GT^T  and  Vt_b = wt2 @ xh_b^T, one 1536-block launch
    proj_dual<<<dim3(16, 6, 16), 256, 0, stream>>>(xh, GT, XG, wt2, Vt);
    // wh dead from here; R aliases it
    hipMemsetAsync(R, 0, 8 * 2048 * sizeof(float), stream);
    // Ps_b = exp(XG_b @ xh_b^T - 12) + rowsum atomics (M=2048,N=2048,K=768)
    gemm_bt<1, f16><<<dim3(16, 16, 8), 256, 0, stream>>>(
        XG, xh, Sc, R, 768, 768, 768, 2048, 1572864, 1572864, 4194304, 1.0f);
    // out_b = (Ps_b @ Vt_b^T) / R[row]  (M=2048, N=768, K=2048), fp32 out
    gemm_bt<2, float><<<dim3(6, 16, 8), 256, 0, stream>>>(
        Sc, Vt, out, R, 2048, 2048, 2048, 768, 4194304, 1572864, 1572864, 1.0f);
}